// Round 2
// baseline (250.043 us; speedup 1.0000x reference)
//
#include <hip/hip_runtime.h>

#define B_ 4
#define T_ 2048
#define H_ 8
#define E_ 64
#define KDIM 512

typedef unsigned short ushort_t;
typedef __attribute__((ext_vector_type(4))) float f32x4;
typedef __attribute__((ext_vector_type(8))) short s16x8;

// fold (1/e^0.25) * sqrt(log2(e)) into both Wq and Wk -> logits arrive pre-multiplied by log2(e)
#define QK_SCALE 0.42466043f

__device__ __forceinline__ ushort_t f2bf(float f) {
  unsigned u = __builtin_bit_cast(unsigned, f);
  u += 0x7fffu + ((u >> 16) & 1u);
  return (ushort_t)(u >> 16);
}

// ---------------- weight prep: transpose to [N][K] bf16, fold scales ----------------
__global__ void k_prep(const float* __restrict__ Wq, const float* __restrict__ Wk,
                       const float* __restrict__ Wv, ushort_t* __restrict__ wt) {
  int z = blockIdx.y;                       // 0=Q 1=K 2=V
  int tid = blockIdx.x * 256 + threadIdx.x; // 0..262143
  int k = tid >> 9, n = tid & 511;
  const float* W = (z == 0) ? Wq : (z == 1 ? Wk : Wv);
  float scale = (z < 2) ? QK_SCALE : 1.0f;
  wt[z * 262144 + n * 512 + k] = f2bf(W[k * 512 + n] * scale);
}

// ---------------- merge-weight softmax over heads: wgt[h][e] ------------------------
__global__ void k_wgt(const float* __restrict__ mw, float* __restrict__ wgt) {
  int e = threadIdx.x;  // 64 threads
  float w[8], wmax = -1e30f;
  for (int h = 0; h < 8; h++) { w[h] = mw[h * 64 + e]; wmax = fmaxf(wmax, w[h]); }
  float wsum = 0.f;
  for (int h = 0; h < 8; h++) { w[h] = __expf(w[h] - wmax); wsum += w[h]; }
  float inv = 1.f / wsum;
  for (int h = 0; h < 8; h++) wgt[h * 64 + e] = w[h] * inv;
}

// ---------------- fused QKV projection GEMM (bf16 MFMA, 128x128 tile, BK=32) --------
__global__ __launch_bounds__(256) void k_proj(
    const float* __restrict__ obs, const float* __restrict__ st,
    const ushort_t* __restrict__ wt,
    ushort_t* __restrict__ qo, ushort_t* __restrict__ ko, ushort_t* __restrict__ vto) {
  __shared__ __align__(16) ushort_t As[128][40];  // +8 pad keeps 16B align, breaks conflicts
  __shared__ __align__(16) ushort_t Bs[128][40];

  int yt = blockIdx.y;          // 0..11
  int which = yt >> 2;          // 0=Q 1=K 2=V
  int n0 = (yt & 3) << 7;       // col tile within 512
  int m0 = blockIdx.x << 7;
  const float* X = (which == 0) ? obs : st;
  const ushort_t* W = wt + which * 262144;

  int tid = threadIdx.x;
  int wave = tid >> 6, lane = tid & 63;
  int l15 = lane & 15, quad = lane >> 4;

  f32x4 acc[2][8];
  for (int i = 0; i < 2; i++)
    for (int j = 0; j < 8; j++) acc[i][j] = (f32x4){0.f, 0.f, 0.f, 0.f};

  int ar = tid >> 1;
  int ac = (tid & 1) << 4;

  for (int k0 = 0; k0 < KDIM; k0 += 32) {
    // stage A: fp32 -> bf16 during staging
    const float* xp = X + (size_t)(m0 + ar) * KDIM + k0 + ac;
    float4 x0 = ((const float4*)xp)[0];
    float4 x1 = ((const float4*)xp)[1];
    float4 x2 = ((const float4*)xp)[2];
    float4 x3 = ((const float4*)xp)[3];
    unsigned p[8];
    p[0] = f2bf(x0.x) | ((unsigned)f2bf(x0.y) << 16);
    p[1] = f2bf(x0.z) | ((unsigned)f2bf(x0.w) << 16);
    p[2] = f2bf(x1.x) | ((unsigned)f2bf(x1.y) << 16);
    p[3] = f2bf(x1.z) | ((unsigned)f2bf(x1.w) << 16);
    p[4] = f2bf(x2.x) | ((unsigned)f2bf(x2.y) << 16);
    p[5] = f2bf(x2.z) | ((unsigned)f2bf(x2.w) << 16);
    p[6] = f2bf(x3.x) | ((unsigned)f2bf(x3.y) << 16);
    p[7] = f2bf(x3.z) | ((unsigned)f2bf(x3.w) << 16);
    *(uint4*)&As[ar][ac] = *(uint4*)&p[0];
    *(uint4*)&As[ar][ac + 8] = *(uint4*)&p[4];
    // stage B (already bf16, [N][K] layout)
    const ushort_t* wp = W + (size_t)(n0 + ar) * KDIM + k0 + ac;
    uint4 w0 = ((const uint4*)wp)[0];
    uint4 w1 = ((const uint4*)wp)[1];
    *(uint4*)&Bs[ar][ac] = w0;
    *(uint4*)&Bs[ar][ac + 8] = w1;
    __syncthreads();

    s16x8 a0 = *(const s16x8*)&As[wave * 32 + l15][quad * 8];
    s16x8 a1 = *(const s16x8*)&As[wave * 32 + 16 + l15][quad * 8];
    for (int nt = 0; nt < 8; nt++) {
      s16x8 b = *(const s16x8*)&Bs[nt * 16 + l15][quad * 8];
      acc[0][nt] = __builtin_amdgcn_mfma_f32_16x16x32_bf16(a0, b, acc[0][nt], 0, 0, 0);
      acc[1][nt] = __builtin_amdgcn_mfma_f32_16x16x32_bf16(a1, b, acc[1][nt], 0, 0, 0);
    }
    __syncthreads();
  }

  // epilogue: C row=(lane>>4)*4+reg, col=lane&15 (verified gfx950 layout)
  for (int mt = 0; mt < 2; mt++) {
    int growb = m0 + wave * 32 + mt * 16 + quad * 4;
    for (int nt = 0; nt < 8; nt++) {
      int gcol = n0 + nt * 16 + l15;
      int h = gcol >> 6, e = gcol & 63;
      for (int r = 0; r < 4; r++) {
        int row = growb + r;
        int bb = row >> 11, t = row & 2047;
        int bh = bb * H_ + h;
        ushort_t val = f2bf(acc[mt][nt][r]);
        if (which == 0)      qo[(((size_t)bh * T_ + t) << 6) + e] = val;
        else if (which == 1) ko[(((size_t)bh * T_ + t) << 6) + e] = val;
        else                 vto[(((size_t)bh << 6) + e) * T_ + t] = val;  // V stored transposed
      }
    }
  }
}

// ---------------- flash attention: one block per (bh, 128-row Q tile) ----------------
union KPU {
  ushort_t ks[128][72];      // K tile [key][e], used during QK^T
  ushort_t ps[4][32][136];   // P tiles per wave, used during PV (aliased after barrier)
};

__global__ __launch_bounds__(256, 2) void k_attn(
    const ushort_t* __restrict__ q, const ushort_t* __restrict__ k,
    const ushort_t* __restrict__ vt, const float* __restrict__ wgt,
    float* __restrict__ out) {
  __shared__ __align__(16) KPU KP;
  __shared__ __align__(16) ushort_t Vs[64][136];  // V^T tile [e][key]

  int qt = blockIdx.x;   // 0..15
  int bh = blockIdx.y;   // 0..31
  int tid = threadIdx.x;
  int wave = tid >> 6, lane = tid & 63;
  int l15 = lane & 15, quad = lane >> 4;

  // head-merge weights for this head, for the 4 e-columns this lane owns
  int hh = bh & 7;
  float wg[4];
  for (int et = 0; et < 4; et++) wg[et] = wgt[hh * 64 + et * 16 + l15];

  // Q fragments held in registers for the whole K loop. A-layout: A[m=lane&15][k=quad*8+j]
  s16x8 qf[2][2];
  for (int mt = 0; mt < 2; mt++)
    for (int kc = 0; kc < 2; kc++) {
      const ushort_t* qp = q + (((size_t)bh * T_ + qt * 128 + wave * 32 + mt * 16 + l15) << 6)
                           + kc * 32 + quad * 8;
      qf[mt][kc] = *(const s16x8*)qp;
    }

  f32x4 o[2][4];
  for (int i = 0; i < 2; i++)
    for (int j = 0; j < 4; j++) o[i][j] = (f32x4){0.f, 0.f, 0.f, 0.f};
  float mst[2][4], lst[2][4];
  for (int i = 0; i < 2; i++)
    for (int r = 0; r < 4; r++) { mst[i][r] = -1e30f; lst[i][r] = 0.f; }

  int key = tid >> 1, hf = tid & 1;
  int ve = tid >> 2, vq = tid & 3;

  for (int kt = 0; kt < 16; kt++) {
    // ---- stage K tile and V^T tile ----
    {
      const ushort_t* kp = k + (((size_t)bh * T_ + kt * 128 + key) << 6) + hf * 32;
      uint4 v0 = ((const uint4*)kp)[0];
      uint4 v1 = ((const uint4*)kp)[1];
      uint4 v2 = ((const uint4*)kp)[2];
      uint4 v3 = ((const uint4*)kp)[3];
      *(uint4*)&KP.ks[key][hf * 32 + 0]  = v0;
      *(uint4*)&KP.ks[key][hf * 32 + 8]  = v1;
      *(uint4*)&KP.ks[key][hf * 32 + 16] = v2;
      *(uint4*)&KP.ks[key][hf * 32 + 24] = v3;
      const ushort_t* vp = vt + (((size_t)bh << 6) + ve) * T_ + kt * 128 + vq * 32;
      uint4 u0 = ((const uint4*)vp)[0];
      uint4 u1 = ((const uint4*)vp)[1];
      uint4 u2 = ((const uint4*)vp)[2];
      uint4 u3 = ((const uint4*)vp)[3];
      *(uint4*)&Vs[ve][vq * 32 + 0]  = u0;
      *(uint4*)&Vs[ve][vq * 32 + 8]  = u1;
      *(uint4*)&Vs[ve][vq * 32 + 16] = u2;
      *(uint4*)&Vs[ve][vq * 32 + 24] = u3;
    }
    __syncthreads();

    // ---- S = Q K^T (logits pre-scaled by log2e via weight folding) ----
    f32x4 s[2][8];
    for (int i = 0; i < 2; i++)
      for (int j = 0; j < 8; j++) s[i][j] = (f32x4){0.f, 0.f, 0.f, 0.f};
    for (int kc = 0; kc < 2; kc++) {
      for (int nt = 0; nt < 8; nt++) {
        s16x8 kf = *(const s16x8*)&KP.ks[nt * 16 + l15][kc * 32 + quad * 8];
        s[0][nt] = __builtin_amdgcn_mfma_f32_16x16x32_bf16(qf[0][kc], kf, s[0][nt], 0, 0, 0);
        s[1][nt] = __builtin_amdgcn_mfma_f32_16x16x32_bf16(qf[1][kc], kf, s[1][nt], 0, 0, 0);
      }
    }
    __syncthreads();  // everyone done reading ks before ps overwrites the union

    // ---- online softmax (row stats live in the 16 lanes of each quad) ----
    for (int mt = 0; mt < 2; mt++) {
      float rmax[4], rsum[4], alpha[4];
      for (int r = 0; r < 4; r++) {
        float m = s[mt][0][r];
        for (int nt = 1; nt < 8; nt++) m = fmaxf(m, s[mt][nt][r]);
        rmax[r] = m;
      }
      for (int mask = 1; mask < 16; mask <<= 1)
        for (int r = 0; r < 4; r++)
          rmax[r] = fmaxf(rmax[r], __shfl_xor(rmax[r], mask, 64));
      for (int r = 0; r < 4; r++) {
        float mnew = fmaxf(mst[mt][r], rmax[r]);
        alpha[r] = exp2f(mst[mt][r] - mnew);
        mst[mt][r] = mnew;
        rsum[r] = 0.f;
      }
      for (int nt = 0; nt < 8; nt++)
        for (int r = 0; r < 4; r++) {
          float p = exp2f(s[mt][nt][r] - mst[mt][r]);
          s[mt][nt][r] = p;
          rsum[r] += p;
        }
      for (int mask = 1; mask < 16; mask <<= 1)
        for (int r = 0; r < 4; r++)
          rsum[r] += __shfl_xor(rsum[r], mask, 64);
      for (int r = 0; r < 4; r++) lst[mt][r] = lst[mt][r] * alpha[r] + rsum[r];
      for (int et = 0; et < 4; et++)
        for (int r = 0; r < 4; r++) o[mt][et][r] *= alpha[r];
      // P: C-layout -> LDS (row-major) so PV can read A-layout fragments
      for (int nt = 0; nt < 8; nt++)
        for (int r = 0; r < 4; r++)
          KP.ps[wave][mt * 16 + quad * 4 + r][nt * 16 + l15] = f2bf(s[mt][nt][r]);
    }
    asm volatile("" ::: "memory");  // keep compiler from hoisting PV reads above P writes

    // ---- O += P V  (per-wave private P region; LDS ops in-order within a wave) ----
    for (int kc2 = 0; kc2 < 4; kc2++) {
      s16x8 pa0 = *(const s16x8*)&KP.ps[wave][l15][kc2 * 32 + quad * 8];
      s16x8 pa1 = *(const s16x8*)&KP.ps[wave][16 + l15][kc2 * 32 + quad * 8];
      for (int et = 0; et < 4; et++) {
        s16x8 bv = *(const s16x8*)&Vs[et * 16 + l15][kc2 * 32 + quad * 8];
        o[0][et] = __builtin_amdgcn_mfma_f32_16x16x32_bf16(pa0, bv, o[0][et], 0, 0, 0);
        o[1][et] = __builtin_amdgcn_mfma_f32_16x16x32_bf16(pa1, bv, o[1][et], 0, 0, 0);
      }
    }
    __syncthreads();  // ks/ps + Vs reused next iteration
  }

  // ---- epilogue: O / l, apply head-merge weight, atomic-accumulate into out ----
  int bb = bh >> 3;
  for (int mt = 0; mt < 2; mt++)
    for (int r = 0; r < 4; r++) {
      int trow = qt * 128 + wave * 32 + mt * 16 + quad * 4 + r;
      float inv = 1.f / lst[mt][r];
      for (int et = 0; et < 4; et++) {
        int e = et * 16 + l15;
        atomicAdd(&out[(((size_t)bb * T_ + trow) << 6) + e], o[mt][et][r] * inv * wg[et]);
      }
    }
}

extern "C" void kernel_launch(void* const* d_in, const int* in_sizes, int n_in,
                              void* d_out, int out_size, void* d_ws, size_t ws_size,
                              hipStream_t stream) {
  const float* obs = (const float*)d_in[0];
  const float* st  = (const float*)d_in[1];
  const float* Wq  = (const float*)d_in[2];
  const float* Wk  = (const float*)d_in[3];
  const float* Wv  = (const float*)d_in[4];
  const float* mw  = (const float*)d_in[5];

  // ws layout (26 MB total)
  const size_t WS_NEEDED = 27262976;
  char* ws = (char*)d_ws;
  ushort_t* wt  = (ushort_t*)ws;                     // 3 * 512*512 bf16 = 1.5 MB @ 0
  float*    wgt = (float*)(ws + 1572864u);           // 8*64 fp32 = 2 KB
  ushort_t* qo  = (ushort_t*)(ws + 2097152u);        // [B,H,T,E] bf16, 8 MB
  ushort_t* ko  = (ushort_t*)(ws + 10485760u);       // [B,H,T,E] bf16, 8 MB
  ushort_t* vto = (ushort_t*)(ws + 18874368u);       // [B,H,E,T] bf16, 8 MB
  float*    out = (float*)d_out;

  // output is accumulated atomically across heads -> zero it first (capture-legal)
  hipMemsetAsync(d_out, 0, (size_t)out_size * sizeof(float), stream);

  if (ws_size < WS_NEEDED) return;  // graceful: zero output, clean absmax signature

  hipLaunchKernelGGL(k_prep, dim3(1024, 3), dim3(256), 0, stream, Wq, Wk, Wv, wt);
  hipLaunchKernelGGL(k_wgt,  dim3(1),       dim3(64),  0, stream, mw, wgt);
  hipLaunchKernelGGL(k_proj, dim3(64, 12),  dim3(256), 0, stream, obs, st, wt, qo, ko, vto);
  hipLaunchKernelGGL(k_attn, dim3(16, 32),  dim3(256), 0, stream, qo, ko, vto, wgt, out);
}